// Round 6
// baseline (367.673 us; speedup 1.0000x reference)
//
#include <hip/hip_runtime.h>

#define SEQ 512
#define BATCH 1024
#define NT 64
#define BT (BATCH * NT)        // float stride between timesteps in emissions
#define GC 16                  // chains per group (one wave)
#define NGROUP (BATCH / GC)    // 64 denominator blocks
#define CHUNK 4                // steps per staged emission chunk
#define NUMER_BLOCKS 512
#define LN2F 0.69314718055994531f

typedef __attribute__((ext_vector_type(8))) short short8;
typedef __attribute__((ext_vector_type(4))) float f32x4;
typedef __attribute__((ext_vector_type(4))) unsigned u32x4;

__device__ __forceinline__ unsigned cvt_pk_bf16(float lo, float hi) {
    unsigned r;
    asm("v_cvt_pk_bf16_f32 %0, %1, %2" : "=v"(r) : "v"(lo), "v"(hi));
    return r;
}

__device__ __forceinline__ short8 mk8(const unsigned* u) {
    u32x4 t = {u[0], u[1], u[2], u[3]};
    return __builtin_bit_cast(short8, t);
}

// Denominator: 16 chains per wave, forward algorithm in linear domain.
// Step = 8x mfma_f32_16x16x32_bf16 (A = E^T resident bf16), then per-lane
// epilogue (*exp(em)*scale), bf16 pack, LDS turnaround C-layout -> B-layout
// (provably correct for any true A/B fragment layout: A and B use the same
// believed k-mapping, which cancels; C layout is the HW-verified one).
// Per-chain freeze at lengths[b]; power-of-2 rescale with stale-by-one k.
__global__ __launch_bounds__(64, 1) void crf_fused(
    const float* __restrict__ em, const int* __restrict__ tags,
    const int* __restrict__ lens, const float* __restrict__ st,
    const float* __restrict__ en, const float* __restrict__ tr,
    float* __restrict__ out)
{
    __shared__ __align__(16) float em_lds[2][CHUNK][GC][NT];   // 32 KB
    __shared__ unsigned y_lds[32 * 17];                        // pair-packed, padded
    const int lane = threadIdx.x;
    const int c  = lane & 15;      // chain within group / MFMA col
    const int hi = lane >> 4;      // 0..3

    if (blockIdx.x < NGROUP) {
        const int cb = blockIdx.x * GC;
        const int Lc = lens[cb + c];
        int maxL = Lc;
        #pragma unroll
        for (int d = 1; d < 16; d <<= 1) maxL = max(maxL, __shfl_xor(maxL, d));

        // ---- A-frags: E^T tiles, believed layout k = 32f + 8hi + 2j2 + {0,1},
        //      row m = 16t + c.  E^T[m][k] = exp(trans[k][m]).
        unsigned Au[4][2][4];
        #pragma unroll
        for (int t = 0; t < 4; ++t)
            #pragma unroll
            for (int f = 0; f < 2; ++f)
                #pragma unroll
                for (int j2 = 0; j2 < 4; ++j2) {
                    int k = 32 * f + 8 * hi + 2 * j2;
                    int m = 16 * t + c;
                    Au[t][f][j2] = cvt_pk_bf16(__expf(tr[k * NT + m]),
                                               __expf(tr[(k + 1) * NT + m]));
                }
        short8 A8[4][2];
        #pragma unroll
        for (int t = 0; t < 4; ++t) {
            A8[t][0] = mk8(Au[t][0]);
            A8[t][1] = mk8(Au[t][1]);
        }

        // ---- B init: p0[k] = exp(st[k] + em0[k] - xs), xs = st[0]+em0[0] ----
        const float xs = st[0] + em[(size_t)(cb + c) * NT];
        unsigned Bu[2][4];
        #pragma unroll
        for (int f = 0; f < 2; ++f)
            #pragma unroll
            for (int j2 = 0; j2 < 4; ++j2) {
                int k = 32 * f + 8 * hi + 2 * j2;
                float p0 = __expf(st[k]     + em[(size_t)(cb + c) * NT + k]     - xs);
                float p1 = __expf(st[k + 1] + em[(size_t)(cb + c) * NT + k + 1] - xs);
                Bu[f][j2] = cvt_pk_bf16(p0, p1);
            }

        // ---- emission chunk staging (R4-proven machinery) ----
        auto stage = [&](int ch) {
            const int sb = ch * CHUNK;
            #pragma unroll
            for (int i = 0; i < CHUNK; ++i)
                #pragma unroll
                for (int q = 0; q < 4; ++q) {
                    const float* g = em + (size_t)(sb + i) * BT + cb * NT
                                     + q * 256 + lane * 4;
                    __builtin_amdgcn_global_load_lds(
                        (const __attribute__((address_space(1))) void*)g,
                        (__attribute__((address_space(3))) void*)
                            (&em_lds[ch & 1][i][0][0] + q * 256),
                        16, 0, 0);
                }
        };
        const int nch = (maxL + CHUNK - 1) / CHUNK;
        stage(0);
        asm volatile("s_waitcnt vmcnt(0)" ::: "memory");
        if (nch > 1) stage(1);

        int ksum = 0, pend_k = 0;
        float pend_scale = 1.0f;
        const f32x4 zacc = {0.f, 0.f, 0.f, 0.f};

        for (int s = 1; s < maxL; ++s) {
            const int ch = s >> 2;
            if ((s & 3) == 0) {
                asm volatile("s_waitcnt vmcnt(0)" ::: "memory");
                if (ch + 1 < nch) stage(ch + 1);
            }

            // ---- 8x MFMA: acc[t] = E^T-tile-t x P ----
            short8 B0 = mk8(Bu[0]), B1 = mk8(Bu[1]);
            f32x4 acc[4];
            #pragma unroll
            for (int t = 0; t < 4; ++t) {
                acc[t] = __builtin_amdgcn_mfma_f32_16x16x32_bf16(
                    A8[t][0], B0, zacc, 0, 0, 0);
                acc[t] = __builtin_amdgcn_mfma_f32_16x16x32_bf16(
                    A8[t][1], B1, acc[t], 0, 0, 0);
            }

            // ---- epilogue: y = acc * exp(em) * pend_scale; pack; LDS write ----
            // C layout (verified): row = 16t + 4hi + r, col(chain) = c.
            const float4* erow = reinterpret_cast<const float4*>(
                &em_lds[ch & 1][s & 3][c][0]);
            #pragma unroll
            for (int t = 0; t < 4; ++t) {
                float4 e4 = erow[4 * t + hi];
                float y0 = fminf(acc[t][0] * __expf(e4.x) * pend_scale, 1e30f);
                float y1 = fminf(acc[t][1] * __expf(e4.y) * pend_scale, 1e30f);
                float y2 = fminf(acc[t][2] * __expf(e4.z) * pend_scale, 1e30f);
                float y3 = fminf(acc[t][3] * __expf(e4.w) * pend_scale, 1e30f);
                y_lds[(8 * t + 2 * hi)     * 17 + c] = cvt_pk_bf16(y0, y1);
                y_lds[(8 * t + 2 * hi + 1) * 17 + c] = cvt_pk_bf16(y2, y3);
            }

            // rep = state-0 of chain c (same-address broadcast within chain)
            unsigned u00 = y_lds[c];

            const bool live = (s < Lc);
            if (live) ksum += pend_k;

            // ---- read back into B slots (believed pair = 16f + 4hi + j2) ----
            #pragma unroll
            for (int f = 0; f < 2; ++f)
                #pragma unroll
                for (int j2 = 0; j2 < 4; ++j2) {
                    unsigned v = y_lds[(16 * f + 4 * hi + j2) * 17 + c];
                    Bu[f][j2] = live ? v : Bu[f][j2];
                }

            // ---- next-step scale from bf16 exponent of rep (stale-by-one) ----
            int kk = (int)((u00 >> 7) & 255) - 127;
            kk = kk < -126 ? -126 : (kk > 126 ? 126 : kk);
            pend_k = kk;
            pend_scale = __uint_as_float((unsigned)(127 - kk) << 23); // 2^-kk
        }

        // ---- final: denom_c = xs + ksum*ln2 + log(sum_k p[k]*exp(en[k])) ----
        float part = 0.f;
        #pragma unroll
        for (int f = 0; f < 2; ++f)
            #pragma unroll
            for (int j2 = 0; j2 < 4; ++j2) {
                unsigned u = Bu[f][j2];
                int k0 = 32 * f + 8 * hi + 2 * j2;
                part += __uint_as_float(u << 16)          * __expf(en[k0]);
                part += __uint_as_float(u & 0xffff0000u)  * __expf(en[k0 + 1]);
            }
        part += __shfl_xor(part, 16);
        part += __shfl_xor(part, 32);
        part = fmaxf(part, 1e-35f);
        if (lane < 16)
            atomicAdd(out, -(xs + (float)ksum * LN2F + __logf(part)));
    } else {
        // ---------------- numerator: tag-path score (grid-stride gather) -------
        const int t0 = (blockIdx.x - NGROUP) * 64 + lane;
        float acc = 0.f;
        for (int idx = t0; idx < SEQ * BATCH; idx += NUMER_BLOCKS * 64) {
            int b = idx & (BATCH - 1);
            int s = idx >> 10;
            int L = lens[b];
            int tg = tags[s * BATCH + b];
            float v = 0.f;
            if (s == 0) {
                v = st[tg] + em[(size_t)b * NT + tg];
            } else if (s < L) {
                int tp = tags[(s - 1) * BATCH + b];
                v = tr[tp * NT + tg] + em[(size_t)s * BT + (size_t)b * NT + tg];
            }
            if (s == L - 1) v += en[tg];
            acc += v;
        }
        #pragma unroll
        for (int d = 32; d > 0; d >>= 1) acc += __shfl_xor(acc, d);
        if (lane == 0) atomicAdd(out, acc);
    }
}

extern "C" void kernel_launch(void* const* d_in, const int* in_sizes, int n_in,
                              void* d_out, int out_size, void* d_ws, size_t ws_size,
                              hipStream_t stream)
{
    const float* emissions = (const float*)d_in[0];
    const int*   tags      = (const int*)d_in[1];
    const int*   lengths   = (const int*)d_in[2];
    const float* start_tr  = (const float*)d_in[3];
    const float* end_tr    = (const float*)d_in[4];
    const float* trans     = (const float*)d_in[5];
    float* out = (float*)d_out;

    hipMemsetAsync(out, 0, sizeof(float), stream);

    crf_fused<<<NGROUP + NUMER_BLOCKS, 64, 0, stream>>>(
        emissions, tags, lengths, start_tr, end_tr, trans, out);
}